// Round 10
// baseline (329.228 us; speedup 1.0000x reference)
//
#include <hip/hip_runtime.h>

#define B_ 2
#define T_ 2048
#define NH 16
#define NKV 8
#define HD 128
#define C_ 2048
#define KVD (NKV*HD)       // 1024
#define QKVD (C_ + 2*KVD)  // 4096
#define NTOK (B_*T_)       // 4096

typedef __bf16 bf16_t;
typedef __bf16 bf16x2_t __attribute__((ext_vector_type(2)));
typedef __bf16 bf16x4_t __attribute__((ext_vector_type(4)));
typedef __bf16 bf16x8_t __attribute__((ext_vector_type(8)));
typedef float f32x4_t __attribute__((ext_vector_type(4)));
typedef float f32x16_t __attribute__((ext_vector_type(16)));
typedef int i32x4_t __attribute__((ext_vector_type(4)));

__device__ __forceinline__ f32x4_t mfma16(bf16x8_t a, bf16x8_t b, f32x4_t c) {
  return __builtin_amdgcn_mfma_f32_16x16x32_bf16(a, b, c, 0, 0, 0);
}
__device__ __forceinline__ f32x16_t mfma32(bf16x8_t a, bf16x8_t b, f32x16_t c) {
  return __builtin_amdgcn_mfma_f32_32x32x16_bf16(a, b, c, 0, 0, 0);
}
__device__ __forceinline__ f32x16_t zero16() {
  f32x16_t z;
  #pragma unroll
  for (int i = 0; i < 16; i++) z[i] = 0.f;
  return z;
}
__device__ __forceinline__ int pk2(float a, float b) {
  bf16x2_t t; t[0] = (bf16_t)a; t[1] = (bf16_t)b;
  return __builtin_bit_cast(int, t);
}

// async global->LDS, 16B per lane
#define GLDS16(gp, lp) __builtin_amdgcn_global_load_lds( \
    (const __attribute__((address_space(1))) void*)(gp), \
    (__attribute__((address_space(3))) void*)(lp), 16, 0, 0)

#define CFENCE() asm volatile("" ::: "memory")

// LDS row strides for attn tiles: stride(dwords) mod 32 == 2 -> column-slice reads are
// 2-way bank-aliased only (free, m136).
#define KSTR 132
#define VSTR 68

// ---------------- fused fp32 -> bf16 convert for x / w_attn / w_proj ----------------
__global__ __launch_bounds__(256) void cvt3_kernel(const float* __restrict__ s0, bf16_t* __restrict__ d0,
                                                   const float* __restrict__ s1, bf16_t* __restrict__ d1,
                                                   const float* __restrict__ s2, bf16_t* __restrict__ d2) {
  int bid = blockIdx.x;
  const float* s; bf16_t* d; int off;
  if (bid < 8192)       { s = s0; d = d0; off = bid; }
  else if (bid < 16384) { s = s1; d = d1; off = bid - 8192; }
  else                  { s = s2; d = d2; off = bid - 16384; }
  int i = (off * 256 + threadIdx.x) * 4;
  const float4 v = *(const float4*)(s + i);
  bf16x4_t o;
  o[0] = (bf16_t)v.x; o[1] = (bf16_t)v.y; o[2] = (bf16_t)v.z; o[3] = (bf16_t)v.w;
  *(bf16x4_t*)(d + i) = o;
}

// ---------------- 8-phase 256x256 bf16 NT GEMM (round-9, verified): C = A B^T, bf16 out ----------------
__global__ __launch_bounds__(512, 1) void gemm8p(const bf16_t* __restrict__ A,
                                                 const bf16_t* __restrict__ Bm,
                                                 bf16_t* __restrict__ Cb,
                                                 int M, int N, int K) {
  __shared__ __align__(16) bf16_t As[2][256 * 64];
  __shared__ __align__(16) bf16_t Bs[2][256 * 64];
  int tid = threadIdx.x;
  int wave = tid >> 6, lane = tid & 63;
  int quad = lane >> 4, l16 = lane & 15;
  int wm = wave >> 2, wn = wave & 3;
  int gx = gridDim.x, nwg = gx * gridDim.y;
  int flat = blockIdx.y * gx + blockIdx.x;
  int swz = (flat & 7) * (nwg >> 3) + (flat >> 3);
  int bm = (swz / gx) * 256, bn = (swz % gx) * 256;
  int scol = ((tid & 7) ^ ((tid >> 3) & 7)) * 8;
  int srow = tid >> 3;                 // 0..63
  const bf16_t* pa = A + (size_t)(bm + srow) * K + scol;
  const bf16_t* pb = Bm + (size_t)(bn + srow) * K + scol;

#define STAGE_A8(buf, tile, h) { \
    GLDS16(pa + (size_t)((h)*128 + 0) * K + (size_t)(tile)*64, &As[buf][((h)*128 + 0 + wave*8)*64]); \
    GLDS16(pa + (size_t)((h)*128 + 64) * K + (size_t)(tile)*64, &As[buf][((h)*128 + 64 + wave*8)*64]); }
#define STAGE_B8(buf, tile, h) { \
    GLDS16(pb + (size_t)((h)*128 + 0) * K + (size_t)(tile)*64, &Bs[buf][((h)*128 + 0 + wave*8)*64]); \
    GLDS16(pb + (size_t)((h)*128 + 64) * K + (size_t)(tile)*64, &Bs[buf][((h)*128 + 64 + wave*8)*64]); }

  f32x4_t acc[8][4];
  #pragma unroll
  for (int i = 0; i < 8; i++)
    #pragma unroll
    for (int j = 0; j < 4; j++) acc[i][j] = (f32x4_t){0.f, 0.f, 0.f, 0.f};

  int nt = K >> 6;                     // 32 (assumes nt >= 3)
  STAGE_A8(0, 0, 0); STAGE_A8(0, 0, 1); STAGE_B8(0, 0, 0); STAGE_B8(0, 0, 1);
  STAGE_B8(1, 1, 0); STAGE_B8(1, 1, 1);
  asm volatile("s_waitcnt vmcnt(4)" ::: "memory");
  CFENCE(); __builtin_amdgcn_s_barrier(); CFENCE();

  for (int s = 0; s < nt; ++s) {
    int b = s & 1;
    bf16x8_t bfr[4][2];
    #pragma unroll
    for (int jph = 0; jph < 4; ++jph) {
      const int kh = jph >> 1;         // K half
      const int mg = jph & 1;          // mi group
      if (mg == 0) {
        #pragma unroll
        for (int ni = 0; ni < 4; ni++)
          bfr[ni][kh] = *(const bf16x8_t*)&Bs[b][(wn*64 + ni*16 + l16)*64 + (((kh*4 + quad) ^ (l16 & 7))*8)];
      }
      bf16x8_t af[4];
      #pragma unroll
      for (int i = 0; i < 4; i++)
        af[i] = *(const bf16x8_t*)&As[b][(wm*128 + (mg*4 + i)*16 + l16)*64 + (((kh*4 + quad) ^ (l16 & 7))*8)];
      if (jph == 0) { if (s + 1 < nt) STAGE_A8(1 - b, s + 1, 0); }
      if (jph == 1) { if (s + 1 < nt) STAGE_A8(1 - b, s + 1, 1); }
      if (jph == 3) {
        if (s + 2 < nt) {
          STAGE_B8(b, s + 2, 0);
          STAGE_B8(b, s + 2, 1);
          asm volatile("s_waitcnt vmcnt(4)" ::: "memory");
        } else {
          asm volatile("s_waitcnt vmcnt(0)" ::: "memory");
        }
      }
      CFENCE(); __builtin_amdgcn_s_barrier(); CFENCE();
      __builtin_amdgcn_s_setprio(1);
      #pragma unroll
      for (int i = 0; i < 4; i++)
        #pragma unroll
        for (int ni = 0; ni < 4; ni++)
          acc[mg*4 + i][ni] = mfma16(af[i], bfr[ni][kh], acc[mg*4 + i][ni]);
      __builtin_amdgcn_s_setprio(0);
      CFENCE(); __builtin_amdgcn_s_barrier(); CFENCE();
    }
  }
  #pragma unroll
  for (int mi = 0; mi < 8; mi++)
    #pragma unroll
    for (int ni = 0; ni < 4; ni++) {
      int row0 = bm + wm*128 + mi*16 + quad*4;
      int col  = bn + wn*64 + ni*16 + l16;
      #pragma unroll
      for (int r = 0; r < 4; r++)
        Cb[(size_t)(row0 + r) * N + col] = (bf16_t)acc[mi][ni][r];
    }
#undef STAGE_A8
#undef STAGE_B8
}

// ---------------- bf16 NT GEMM v2 (2-phase): C = A B^T; out fp32 (Cf) or bf16 (Cb) ----------------
template<int BM>
__global__ __launch_bounds__(512, 1) void gemm_nt2(const bf16_t* __restrict__ A,
                                                   const bf16_t* __restrict__ Bm,
                                                   float* __restrict__ Cf, bf16_t* __restrict__ Cb,
                                                   int M, int N, int K) {
  constexpr int MR = BM / 32;     // m-frags per wave
  constexpr int RA = BM / 64;     // A staging rounds (8KB each)
  __shared__ __align__(16) bf16_t As[2][BM * 64];
  __shared__ __align__(16) bf16_t Bs[2][256 * 64];
  int tid = threadIdx.x;
  int wave = tid >> 6, lane = tid & 63;
  int quad = lane >> 4, l16 = lane & 15;
  int wm = wave >> 2, wn = wave & 3;
  int gx = gridDim.x;
  int nwg = gx * gridDim.y;
  int flat = blockIdx.y * gx + blockIdx.x;
  int swz = (flat & 7) * (nwg >> 3) + (flat >> 3);
  int bm = (swz / gx) * BM, bn = (swz % gx) * 256;
  int scol = (((tid & 7) ^ ((tid >> 3) & 7))) * 8;
  const bf16_t* pa = A + (size_t)(bm + (tid >> 3)) * K + scol;
  const bf16_t* pb = Bm + (size_t)(bn + (tid >> 3)) * K + scol;

  f32x4_t acc[MR][4];
  #pragma unroll
  for (int i = 0; i < MR; i++)
    #pragma unroll
    for (int j = 0; j < 4; j++) acc[i][j] = (f32x4_t){0.f, 0.f, 0.f, 0.f};

  int nt = K >> 6;
  #pragma unroll
  for (int r = 0; r < RA; r++) GLDS16(pa + (size_t)(r * 64) * K, &As[0][(r * 64 + wave * 8) * 64]);
  #pragma unroll
  for (int r = 0; r < 4; r++)  GLDS16(pb + (size_t)(r * 64) * K, &Bs[0][(r * 64 + wave * 8) * 64]);
  __syncthreads();

  for (int t = 0; t < nt; t++) {
    int cur = t & 1;
    if (t + 1 < nt) {
      int k1 = (t + 1) * 64;
      #pragma unroll
      for (int r = 0; r < RA; r++) GLDS16(pa + (size_t)(r * 64) * K + k1, &As[1 - cur][(r * 64 + wave * 8) * 64]);
      #pragma unroll
      for (int r = 0; r < 4; r++)  GLDS16(pb + (size_t)(r * 64) * K + k1, &Bs[1 - cur][(r * 64 + wave * 8) * 64]);
    }
    bf16x8_t bfr[4][2];
    #pragma unroll
    for (int ni = 0; ni < 4; ni++)
      #pragma unroll
      for (int kh = 0; kh < 2; kh++) {
        int blk = (kh * 4 + quad) ^ (l16 & 7);
        bfr[ni][kh] = *(const bf16x8_t*)&Bs[cur][(wn * 64 + ni * 16 + l16) * 64 + blk * 8];
      }
    #pragma unroll
    for (int g = 0; g < MR / 2; g++) {
      bf16x8_t af[2][2];
      #pragma unroll
      for (int i = 0; i < 2; i++)
        #pragma unroll
        for (int kh = 0; kh < 2; kh++) {
          int blk = (kh * 4 + quad) ^ (l16 & 7);
          af[i][kh] = *(const bf16x8_t*)&As[cur][(wm * (BM / 2) + (g * 2 + i) * 16 + l16) * 64 + blk * 8];
        }
      #pragma unroll
      for (int kh = 0; kh < 2; kh++)
        #pragma unroll
        for (int i = 0; i < 2; i++)
          #pragma unroll
          for (int ni = 0; ni < 4; ni++)
            acc[g * 2 + i][ni] = mfma16(af[i][kh], bfr[ni][kh], acc[g * 2 + i][ni]);
    }
    __syncthreads();
  }
  #pragma unroll
  for (int mi = 0; mi < MR; mi++)
    #pragma unroll
    for (int ni = 0; ni < 4; ni++) {
      int row0 = bm + wm * (BM / 2) + mi * 16 + quad * 4;
      int col  = bn + wn * 64 + ni * 16 + l16;
      if (Cb) {
        #pragma unroll
        for (int r = 0; r < 4; r++)
          Cb[(size_t)(row0 + r) * N + col] = (bf16_t)acc[mi][ni][r];
      } else {
        #pragma unroll
        for (int r = 0; r < 4; r++)
          Cf[(size_t)(row0 + r) * N + col] = acc[mi][ni][r];
      }
    }
}

// ---------------- RoPE+RMSNorm AND V-transpose, fused into one launch ----------------
__global__ __launch_bounds__(256) void rope_tv_kernel(const bf16_t* __restrict__ qkv,
    const float* __restrict__ cosb, const float* __restrict__ sinb,
    bf16_t* __restrict__ qb, bf16_t* __restrict__ kb, bf16_t* __restrict__ vt) {
  __shared__ bf16_t TT[64*136];   // transpose scratch (tok, d) pad 128->136
  int bid = blockIdx.x;
  int tid = threadIdx.x;
  if (bid < 24576) {
    int token = bid & 4095;
    int slot = (bid >> 12) * 4 + (tid >> 6);
    int lane = tid & 63;
    int b = token >> 11, s = token & 2047;
    const bf16_t* row = qkv + (size_t)token * QKVD;
    int base_in = (slot < 16) ? slot * HD : C_ + (slot - 16) * HD;
    float x1 = (float)row[base_in + lane];
    float x2 = (float)row[base_in + 64 + lane];
    float c = cosb[s*64 + lane], sn = sinb[s*64 + lane];
    float y1 = x1*c + x2*sn;
    float y2 = x2*c - x1*sn;
    float ss = y1*y1 + y2*y2;
    ss += __shfl_xor(ss, 1);  ss += __shfl_xor(ss, 2);  ss += __shfl_xor(ss, 4);
    ss += __shfl_xor(ss, 8);  ss += __shfl_xor(ss, 16); ss += __shfl_xor(ss, 32);
    float r = rsqrtf(ss * (1.0f/128.0f) + 1.1920929e-07f);
    bf16_t* dst;
    if (slot < 16) {
      r *= 0.08838834764831845f * 1.4426950408889634f;  // 1/sqrt(128) * log2(e)
      dst = qb + ((size_t)(b*NH + slot) * T_ + s) * HD;
    } else {
      dst = kb + ((size_t)(b*NKV + (slot-16)) * T_ + s) * HD;
    }
    dst[lane]      = (bf16_t)(y1 * r);
    dst[lane + 64] = (bf16_t)(y2 * r);
  } else {
    int id = bid - 24576;
    int bk = id & 15;               // b*8 + kv
    int s0 = (id >> 4) * 64;
    int b = bk >> 3, kv = bk & 7;
    int row = tid >> 2, c0 = (tid & 3) * 32;
    const bf16_t* src = qkv + (size_t)(b*T_ + s0 + row) * QKVD + C_ + KVD + kv*HD + c0;
    #pragma unroll
    for (int s4 = 0; s4 < 4; s4++)
      *(bf16x8_t*)&TT[row*136 + c0 + s4*8] = *(const bf16x8_t*)(src + s4*8);
    __syncthreads();
    #pragma unroll
    for (int s2 = 0; s2 < 2; s2++) {
      int d = (tid >> 2) + s2*64;
      #pragma unroll
      for (int s = 0; s < 2; s++) {
        int g = (tid & 3) * 8 + s*32;
        bf16x8_t pk;
        #pragma unroll
        for (int e = 0; e < 8; e++) pk[e] = TT[(g + e)*136 + d];
        *(bf16x8_t*)(vt + ((size_t)bk * HD + d) * T_ + s0 + g) = pk;
      }
    }
  }
}

// ---------------- flash attention: split-K within block, PHASE-SKEWED groups ----------------
// 512 threads = 8 waves; group g = wave>>2 owns key half g, q-slice sq = wave&3.
// SKEW (this round): g0 slot t = {QKT(t); SM(t); PV(t)}; g1 slot t = {SM(t-1); PV(t-1);
// QKT(t)} -- so on each SIMD the g0 wave and g1 wave are in OPPOSITE phases (one VALU-softmax
// while the other LDS/MFMA). Barrier rendezvous is a counter: counts match (h0 in-loop + 2
// merge) even though groups arrive from different program points.
// Hazards: K double-buffered both groups (read t&1, write (t+1)&1 -- disjoint even skewed).
// g1's V is TRIPLE-buffered (ring %3): PV(t-1) reads (t-1)%3, stage(t+1) writes (t+1)%3 --
// distinct; the write target's last reader was slot t-2, barrier-separated. g1 carries sacc
// (sv[2]) across the barrier (+32 VGPR). g1 tail SM+PV(h0-1) runs after loop, BEFORE the
// first merge barrier. LDS: Ks 67584 + Vall[5] 87040 = 154624 <= 160K -> still 1 block/CU.
// (r7 lesson: cross-block merge via device-scope fence = L2 writeback on non-coherent XCDs,
// 5.6x regression -- intra-block skew is the only affordable phase-diversity.)
__global__ __launch_bounds__(512, 1) void attn_kernel(const bf16_t* __restrict__ qb,
    const bf16_t* __restrict__ kb, const bf16_t* __restrict__ vt, bf16_t* __restrict__ yb) {
  __shared__ __align__(16) bf16_t Ks[2][2][64*KSTR];   // [group][buf] (key, d) 67584 B
  __shared__ __align__(16) bf16_t Vall[5][128*VSTR];   // g0: [0,1]; g1: [2,3,4]  87040 B
  int L = blockIdx.x;
  int bh = L & 31;
  int qt = 15 - (L >> 5);              // heavy first
  int b = bh >> 4, h = bh & 15, kvh = h >> 1;
  int tid = threadIdx.x;
  int wv = tid >> 6;                   // 0..7
  int g  = wv >> 2;                    // key group
  int sq = wv & 3;                     // q-slice
  int lane = tid & 63;
  int l32 = lane & 31, half = lane >> 5;
  int t256 = tid & 255;                // within-group thread id (256 per group)
  const bf16_t* Qp = qb + (size_t)bh * T_ * HD;
  const bf16_t* Kp = kb + (size_t)(b*NKV + kvh) * T_ * HD;
  const bf16_t* Vt = vt + (size_t)(b*NKV + kvh) * HD * T_;

  int krow = t256 >> 2, kcb = (t256 & 3) * 32;   // K staging: 64 rows x 128
  int vd = t256 >> 1,  vcb = (t256 & 1) * 32;    // V staging: 128 rows x 64

  int h0 = qt + 1;                     // tiles per group
  int kt0 = g * h0;                    // first tile of this group

  int qrow = qt*128 + sq*32 + l32;
  bf16x8_t qf[8];                      // B-frag: B[k=half*8+jj][n=l32]
  #pragma unroll
  for (int kc = 0; kc < 8; kc++)
    qf[kc] = *(const bf16x8_t*)(Qp + (size_t)qrow * HD + kc*16 + half*8);

  float mrow = -1e30f, lrow = 0.f;
  f32x16_t o[4];                       // O^T: rows = d, col = q = l32
  #pragma unroll
  for (int mb = 0; mb < 4; mb++) o[mb] = zero16();
  f32x16_t sv[2];                      // S acc; g1 carries across barrier

// ---- body macros (compile-time-indexed; _Pragma since #pragma can't nest in #define) ----
#define QKT_BODY(KBASE) { \
    sv[0] = zero16(); sv[1] = zero16(); \
    _Pragma("unroll") \
    for (int kc = 0; kc < 8; kc++) { \
      _Pragma("unroll") \
      for (int mb = 0; mb < 2; mb++) { \
        bf16x8_t kf = *(const bf16x8_t*)&(KBASE)[(mb*32 + l32)*KSTR + kc*16 + half*8]; \
        sv[mb] = mfma32(kf, qf[kc], sv[mb]); \
      } \
    } \
  }
#define MASK_BODY(K0V) { \
    if ((K0V) + 63 > qt*128 + sq*32) { \
      _Pragma("unroll") \
      for (int mb = 0; mb < 2; mb++) { \
        _Pragma("unroll") \
        for (int r = 0; r < 16; r++) { \
          int key = (K0V) + mb*32 + (r&3) + 8*(r>>2) + 4*half; \
          if (key > qrow) sv[mb][r] = -1e30f; \
        } \
      } \
    } \
  }
#define SMPV_BODY(VBASE) { \
    float tm[16]; \
    _Pragma("unroll") \
    for (int r = 0; r < 16; r++) tm[r] = fmaxf(sv[0][r], sv[1][r]); \
    _Pragma("unroll") \
    for (int st = 8; st >= 1; st >>= 1) { \
      _Pragma("unroll") \
      for (int r = 0; r < st; r++) tm[r] = fmaxf(tm[r], tm[r + st]); \
    } \
    float mx = fmaxf(tm[0], __shfl_xor(tm[0], 32)); \
    if (!__all(mx - mrow <= 8.0f)) { \
      float mnew = fmaxf(mrow, mx); \
      float alpha = exp2f(mrow - mnew); \
      mrow = mnew; lrow *= alpha; \
      _Pragma("unroll") \
      for (int mb = 0; mb < 4; mb++) o[mb] = o[mb] * alpha; \
    } \
    _Pragma("unroll") \
    for (int mb = 0; mb < 2; mb++) { \
      _Pragma("unroll") \
      for (int r = 0; r < 16; r++) sv[mb][r] = exp2f(sv[mb][r] - mrow); \
    } \
    float tsum[16]; \
    _Pragma("unroll") \
    for (int r = 0; r < 16; r++) tsum[r] = sv[0][r] + sv[1][r]; \
    _Pragma("unroll") \
    for (int st = 8; st >= 1; st >>= 1) { \
      _Pragma("unroll") \
      for (int r = 0; r < st; r++) tsum[r] += tsum[r + st]; \
    } \
    lrow += tsum[0] + __shfl_xor(tsum[0], 32); \
    int P2[2][4][2]; \
    _Pragma("unroll") \
    for (int mb = 0; mb < 2; mb++) { \
      _Pragma("unroll") \
      for (int gg = 0; gg < 4; gg++) { \
        P2[mb][gg][0] = pk2(sv[mb][4*gg+0], sv[mb][4*gg+1]); \
        P2[mb][gg][1] = pk2(sv[mb][4*gg+2], sv[mb][4*gg+3]); \
      } \
    } \
    _Pragma("unroll") \
    for (int kc = 0; kc < 4; kc++) { \
      int mbq = kc >> 1, c = kc & 1; \
      int o0 = half ? P2[mbq][2*c+1][0] : P2[mbq][2*c][0]; \
      int o1 = half ? P2[mbq][2*c+1][1] : P2[mbq][2*c][1]; \
      int s0 = half ? P2[mbq][2*c][0]   : P2[mbq][2*c+1][0]; \
      int s1 = half ? P2[mbq][2*c][1]   : P2[mbq][2*c+1][1]; \
      int r0 = __shfl_xor(s0, 32); \
      int r1 = __shfl_xor(s1, 32); \
      i32x4_t wvv; \
      wvv[0] = half ? r0 : o0; \
      wvv[1] = half ? r1 : o1; \
      wvv[2] = half ? o0 : r0; \
      wvv[3] = half ? o1 : r1; \
      bf16x8_t pf = __builtin_bit_cast(bf16x8_t, wvv); \
      _Pragma("unroll") \
      for (int mbd = 0; mbd < 4; mbd++) { \
        bf16x8_t vf = *(const bf16x8_t*)&(VBASE)[(mbd*32 + l32)*VSTR + kc*16 + half*8]; \
        o[mbd] = mfma32(vf, pf, o[mbd]); \
      } \
    } \
  }

  bf16x8_t kreg[4], vreg[4];
  // prologue: stage tile kt0 into K buf 0 and V buf (g0: Vall[0], g1: Vall[2])
  {
    const bf16_t* srck = Kp + (size_t)(kt0*64 + krow) * HD + kcb;
    const bf16_t* srcv = Vt + (size_t)vd * T_ + kt0*64 + vcb;
    #pragma unroll
    for (int s2 = 0; s2 < 4; s2++) { kreg[s2] = *(const bf16x8_t*)(srck + s2*8);
                                     vreg[s2] = *(const bf16x8_t*)(srcv + s2*8); }
  }
  {
    bf16_t* v0 = (g == 0) ? Vall[0] : Vall[2];
    #pragma unroll
    for (int s2 = 0; s2 < 4; s2++) { *(bf16x8_t*)&Ks[g][0][krow*KSTR + kcb + s2*8] = kreg[s2];
                                     *(bf16x8_t*)&v0[vd*VSTR + vcb + s2*8] = vreg[s2]; }
  }

  int vq = 0;                          // t % 3 (g1 V ring)
  for (int t = 0; t < h0; t++) {
    __syncthreads();  // staging of this slot's buffers visible; prior readers done
    int cur = t & 1;
    int vqn = (vq == 2) ? 0 : vq + 1;  // (t+1)%3
    int vqp = (vq == 0) ? 2 : vq - 1;  // (t-1)%3
    if (t + 1 < h0) {    // issue next tile's global loads (latency hidden by compute)
      int k1 = (kt0 + t + 1) * 64;
      const bf16_t* srck = Kp + (size_t)(k1 + krow) * HD + kcb;
      const bf16_t* srcv = Vt + (size_t)vd * T_ + k1 + vcb;
      #pragma unroll
      for (int s2 = 0; s2 < 4; s2++) { kreg[s2] = *(const bf16x8_t*)(srck + s2*8);
                                       vreg[s2] = *(const bf16x8_t*)(srcv + s2*8); }
    }
    int k0 = (kt0 + t) * 64;
    if (g == 0) {
      QKT_BODY(Ks[0][cur]);
      MASK_BODY(k0);
      SMPV_BODY(Vall[cur]);
    } else {
      if (t > 0) { SMPV_BODY(Vall[2 + vqp]); }   // finish tile t-1 (V from ring)
      QKT_BODY(Ks[1][cur]);
      MASK_BODY(k0);                             // sv carried to next slot
    }
    if (t + 1 < h0) {  // stage next tile
      bf16_t* vw = (g == 0) ? Vall[1 - cur] : Vall[2 + vqn];
      #pragma unroll
      for (int s2 = 0; s2 < 4; s2++) { *(bf16x8_t*)&Ks[g][1-cur][krow*KSTR + kcb + s2*8] = kreg[s2];
                                       *(bf16x8_t*)&vw[vd*VSTR + vcb + s2*8] = vreg[s2]; }
    }
    vq = vqn;
  }
  // g1 tail: finish its last tile (before any merge barrier)
  if (g == 1) {
    int vqp2 = (vq == 0) ? 2 : vq - 1;           // (h0-1)%3
    SMPV_BODY(Vall[2 + vqp2]);
  }
  // -------- merge the two key-halves (lane-aligned), then epilogue by group 0 --------
  __syncthreads();                     // all V reads (incl. g1 tail) done; Vall reusable
  float* MG = (float*)Vall;            // overlay: 256 slots x 66 f32 = 67584 B (<= 87040)
  int mbase = (sq*64 + lane) * 66;     // stride 66 dwords: 2-way bank alias only (free)
  if (g == 1) {
    #pragma unroll
    for (int mb = 0; mb < 4; mb++)
      #pragma unroll
      for (int r = 0; r < 16; r++) MG[mbase + mb*16 + r] = o[mb][r];
    MG[mbase + 64] = mrow;
    MG[mbase + 65] = lrow;
  }
  __syncthreads();
  if (g == 0) {
    float m1 = MG[mbase + 64], l1v = MG[mbase + 65];
    float mm = fmaxf(mrow, m1);
    float a0 = exp2f(mrow - mm), a1 = exp2f(m1 - mm);
    float invl = 1.0f / (lrow * a0 + l1v * a1);
    a0 *= invl; a1 *= invl;
    // O^T -> LDS transpose (wave-private 32xKSTR region over Ks) -> coalesced stores
    bf16_t* OL = &((bf16_t*)Ks)[sq * (32 * KSTR)];
    #pragma unroll
    for (int mb = 0; mb < 4; mb++)
      #pragma unroll
      for (int rr = 0; rr < 4; rr++) {
        bf16x4_t pk;
        #pragma unroll
        for (int jj = 0; jj < 4; jj++)
          pk[jj] = (bf16_t)(o[mb][rr*4+jj] * a0 + MG[mbase + mb*16 + rr*4 + jj] * a1);
        *(bf16x4_t*)&OL[l32*KSTR + mb*32 + rr*8 + half*4] = pk;
      }
    int tok = qt*128 + sq*32 + l32;
    bf16_t* dst = yb + ((size_t)(b*T_ + tok) * NH + h) * HD + half*64;
    #pragma unroll
    for (int jj = 0; jj < 8; jj++)
      *(bf16x8_t*)(dst + jj*8) = *(const bf16x8_t*)&OL[l32*KSTR + half*64 + jj*8];
  }
#undef QKT_BODY
#undef MASK_BODY
#undef SMPV_BODY
}

extern "C" void kernel_launch(void* const* d_in, const int* in_sizes, int n_in,
                              void* d_out, int out_size, void* d_ws, size_t ws_size,
                              hipStream_t stream) {
  const float* x      = (const float*)d_in[0];
  const float* w_attn = (const float*)d_in[1];
  const float* w_proj = (const float*)d_in[2];
  const float* cosb   = (const float*)d_in[3];
  const float* sinb   = (const float*)d_in[4];
  float* out = (float*)d_out;

  bf16_t* xb   = (bf16_t*)d_ws;           // 8388608
  bf16_t* wab  = xb + 8388608;            // 8388608
  bf16_t* wpb  = wab + 8388608;           // 4194304
  bf16_t* qkvb = wpb + 4194304;           // 16777216
  bf16_t* qb   = qkvb + 16777216;         // 8388608
  bf16_t* kb   = qb + 8388608;            // 4194304
  bf16_t* vt   = kb + 4194304;            // 4194304 (b, kvh, d, t)
  bf16_t* yb   = vt + 4194304;            // 8388608

  cvt3_kernel<<<20480, 256, 0, stream>>>(x, xb, w_attn, wab, w_proj, wpb);

  // qkv = x @ w_attn^T : M=4096, N=4096, K=2048 (bf16 out). 8-phase 256x256, grid 16x16
  gemm8p<<<dim3(16, 16), 512, 0, stream>>>(xb, wab, qkvb, NTOK, QKVD, C_);

  // fused RoPE+RMSNorm (24576 blocks) + V transpose (512 blocks)
  rope_tv_kernel<<<25088, 256, 0, stream>>>(qkvb, cosb, sinb, qb, kb, vt);

  // 512 blocks x 512 threads: phase-skewed split-K, heavy-first, 1 block/CU (151KB LDS)
  attn_kernel<<<512, 512, 0, stream>>>(qb, kb, vt, yb);

  // out = y @ w_proj^T : M=4096, N=2048, K=2048 (fp32 out). 128x256 tiles, grid 8x32=256 blocks
  gemm_nt2<128><<<dim3(8, 32), 512, 0, stream>>>(yb, wpb, out, nullptr, NTOK, C_, C_);
}

// Round 11
// 314.444 us; speedup vs baseline: 1.0470x; 1.0470x over previous
//
#include <hip/hip_runtime.h>

#define B_ 2
#define T_ 2048
#define NH 16
#define NKV 8
#define HD 128
#define C_ 2048
#define KVD (NKV*HD)       // 1024
#define QKVD (C_ + 2*KVD)  // 4096
#define NTOK (B_*T_)       // 4096

typedef __bf16 bf16_t;
typedef __bf16 bf16x2_t __attribute__((ext_vector_type(2)));
typedef __bf16 bf16x4_t __attribute__((ext_vector_type(4)));
typedef __bf16 bf16x8_t __attribute__((ext_vector_type(8)));
typedef float f32x4_t __attribute__((ext_vector_type(4)));
typedef float f32x16_t __attribute__((ext_vector_type(16)));
typedef int i32x4_t __attribute__((ext_vector_type(4)));

__device__ __forceinline__ f32x4_t mfma16(bf16x8_t a, bf16x8_t b, f32x4_t c) {
  return __builtin_amdgcn_mfma_f32_16x16x32_bf16(a, b, c, 0, 0, 0);
}
__device__ __forceinline__ f32x16_t mfma32(bf16x8_t a, bf16x8_t b, f32x16_t c) {
  return __builtin_amdgcn_mfma_f32_32x32x16_bf16(a, b, c, 0, 0, 0);
}
__device__ __forceinline__ f32x16_t zero16() {
  f32x16_t z;
  #pragma unroll
  for (int i = 0; i < 16; i++) z[i] = 0.f;
  return z;
}
__device__ __forceinline__ int pk2(float a, float b) {
  bf16x2_t t; t[0] = (bf16_t)a; t[1] = (bf16_t)b;
  return __builtin_bit_cast(int, t);
}

// async global->LDS, 16B per lane
#define GLDS16(gp, lp) __builtin_amdgcn_global_load_lds( \
    (const __attribute__((address_space(1))) void*)(gp), \
    (__attribute__((address_space(3))) void*)(lp), 16, 0, 0)

#define CFENCE() asm volatile("" ::: "memory")

// LDS row strides for attn tiles: stride(dwords) mod 32 == 2 -> column-slice reads are
// 2-way bank-aliased only (free, m136).
#define KSTR 132
#define VSTR 68

// ---------------- fused fp32 -> bf16 convert for x / w_attn / w_proj ----------------
// r11: 8 floats/lane (2x float4 load, one 16B bf16x8 store) -- was 4 floats with 8B store.
__global__ __launch_bounds__(256) void cvt3_kernel(const float* __restrict__ s0, bf16_t* __restrict__ d0,
                                                   const float* __restrict__ s1, bf16_t* __restrict__ d1,
                                                   const float* __restrict__ s2, bf16_t* __restrict__ d2) {
  int bid = blockIdx.x;
  const float* s; bf16_t* d; int off;
  if (bid < 4096)      { s = s0; d = d0; off = bid; }
  else if (bid < 8192) { s = s1; d = d1; off = bid - 4096; }
  else                 { s = s2; d = d2; off = bid - 8192; }
  int i = (off * 256 + threadIdx.x) * 8;
  const float4 v0 = *(const float4*)(s + i);
  const float4 v1 = *(const float4*)(s + i + 4);
  bf16x8_t o;
  o[0] = (bf16_t)v0.x; o[1] = (bf16_t)v0.y; o[2] = (bf16_t)v0.z; o[3] = (bf16_t)v0.w;
  o[4] = (bf16_t)v1.x; o[5] = (bf16_t)v1.y; o[6] = (bf16_t)v1.z; o[7] = (bf16_t)v1.w;
  *(bf16x8_t*)(d + i) = o;
}

// ---------------- 8-phase 256x256 bf16 NT GEMM (round-5/6 verified): C = A B^T, bf16 out ----------------
__global__ __launch_bounds__(512, 1) void gemm8p(const bf16_t* __restrict__ A,
                                                 const bf16_t* __restrict__ Bm,
                                                 bf16_t* __restrict__ Cb,
                                                 int M, int N, int K) {
  __shared__ __align__(16) bf16_t As[2][256 * 64];
  __shared__ __align__(16) bf16_t Bs[2][256 * 64];
  int tid = threadIdx.x;
  int wave = tid >> 6, lane = tid & 63;
  int quad = lane >> 4, l16 = lane & 15;
  int wm = wave >> 2, wn = wave & 3;
  int gx = gridDim.x, nwg = gx * gridDim.y;
  int flat = blockIdx.y * gx + blockIdx.x;
  int swz = (flat & 7) * (nwg >> 3) + (flat >> 3);
  int bm = (swz / gx) * 256, bn = (swz % gx) * 256;
  int scol = ((tid & 7) ^ ((tid >> 3) & 7)) * 8;
  int srow = tid >> 3;                 // 0..63
  const bf16_t* pa = A + (size_t)(bm + srow) * K + scol;
  const bf16_t* pb = Bm + (size_t)(bn + srow) * K + scol;

#define STAGE_A8(buf, tile, h) { \
    GLDS16(pa + (size_t)((h)*128 + 0) * K + (size_t)(tile)*64, &As[buf][((h)*128 + 0 + wave*8)*64]); \
    GLDS16(pa + (size_t)((h)*128 + 64) * K + (size_t)(tile)*64, &As[buf][((h)*128 + 64 + wave*8)*64]); }
#define STAGE_B8(buf, tile, h) { \
    GLDS16(pb + (size_t)((h)*128 + 0) * K + (size_t)(tile)*64, &Bs[buf][((h)*128 + 0 + wave*8)*64]); \
    GLDS16(pb + (size_t)((h)*128 + 64) * K + (size_t)(tile)*64, &Bs[buf][((h)*128 + 64 + wave*8)*64]); }

  f32x4_t acc[8][4];
  #pragma unroll
  for (int i = 0; i < 8; i++)
    #pragma unroll
    for (int j = 0; j < 4; j++) acc[i][j] = (f32x4_t){0.f, 0.f, 0.f, 0.f};

  int nt = K >> 6;                     // 32 (assumes nt >= 3)
  STAGE_A8(0, 0, 0); STAGE_A8(0, 0, 1); STAGE_B8(0, 0, 0); STAGE_B8(0, 0, 1);
  STAGE_B8(1, 1, 0); STAGE_B8(1, 1, 1);
  asm volatile("s_waitcnt vmcnt(4)" ::: "memory");
  CFENCE(); __builtin_amdgcn_s_barrier(); CFENCE();

  for (int s = 0; s < nt; ++s) {
    int b = s & 1;
    bf16x8_t bfr[4][2];
    #pragma unroll
    for (int jph = 0; jph < 4; ++jph) {
      if (jph == 0) {
        #pragma unroll
        for (int ni = 0; ni < 4; ni++)
          #pragma unroll
          for (int kh = 0; kh < 2; kh++)
            bfr[ni][kh] = *(const bf16x8_t*)&Bs[b][(wn*64 + ni*16 + l16)*64 + (((kh*4 + quad) ^ (l16 & 7))*8)];
      }
      bf16x8_t af[2][2];
      #pragma unroll
      for (int i = 0; i < 2; i++)
        #pragma unroll
        for (int kh = 0; kh < 2; kh++)
          af[i][kh] = *(const bf16x8_t*)&As[b][(wm*128 + (jph*2 + i)*16 + l16)*64 + (((kh*4 + quad) ^ (l16 & 7))*8)];
      if (jph == 0) { if (s + 1 < nt) STAGE_A8(1 - b, s + 1, 0); }
      if (jph == 1) { if (s + 1 < nt) STAGE_A8(1 - b, s + 1, 1); }
      if (jph == 2) { if (s + 2 < nt) STAGE_B8(b, s + 2, 0); }
      if (jph == 3) {
        if (s + 2 < nt) {
          STAGE_B8(b, s + 2, 1);
          asm volatile("s_waitcnt vmcnt(4)" ::: "memory");
        } else {
          asm volatile("s_waitcnt vmcnt(0)" ::: "memory");
        }
      }
      CFENCE(); __builtin_amdgcn_s_barrier(); CFENCE();
      __builtin_amdgcn_s_setprio(1);
      #pragma unroll
      for (int kh = 0; kh < 2; kh++)
        #pragma unroll
        for (int i = 0; i < 2; i++)
          #pragma unroll
          for (int ni = 0; ni < 4; ni++)
            acc[jph*2 + i][ni] = mfma16(af[i][kh], bfr[ni][kh], acc[jph*2 + i][ni]);
      __builtin_amdgcn_s_setprio(0);
      CFENCE(); __builtin_amdgcn_s_barrier(); CFENCE();
    }
  }
  #pragma unroll
  for (int mi = 0; mi < 8; mi++)
    #pragma unroll
    for (int ni = 0; ni < 4; ni++) {
      int row0 = bm + wm*128 + mi*16 + quad*4;
      int col  = bn + wn*64 + ni*16 + l16;
      #pragma unroll
      for (int r = 0; r < 4; r++)
        Cb[(size_t)(row0 + r) * N + col] = (bf16_t)acc[mi][ni][r];
    }
#undef STAGE_A8
#undef STAGE_B8
}

// ---------------- bf16 NT GEMM v2 (2-phase): C = A B^T; out fp32 (Cf) or bf16 (Cb) ----------------
template<int BM>
__global__ __launch_bounds__(512, 1) void gemm_nt2(const bf16_t* __restrict__ A,
                                                   const bf16_t* __restrict__ Bm,
                                                   float* __restrict__ Cf, bf16_t* __restrict__ Cb,
                                                   int M, int N, int K) {
  constexpr int MR = BM / 32;     // m-frags per wave
  constexpr int RA = BM / 64;     // A staging rounds (8KB each)
  __shared__ __align__(16) bf16_t As[2][BM * 64];
  __shared__ __align__(16) bf16_t Bs[2][256 * 64];
  int tid = threadIdx.x;
  int wave = tid >> 6, lane = tid & 63;
  int quad = lane >> 4, l16 = lane & 15;
  int wm = wave >> 2, wn = wave & 3;
  int gx = gridDim.x;
  int nwg = gx * gridDim.y;
  int flat = blockIdx.y * gx + blockIdx.x;
  int swz = (flat & 7) * (nwg >> 3) + (flat >> 3);
  int bm = (swz / gx) * BM, bn = (swz % gx) * 256;
  int scol = (((tid & 7) ^ ((tid >> 3) & 7))) * 8;
  const bf16_t* pa = A + (size_t)(bm + (tid >> 3)) * K + scol;
  const bf16_t* pb = Bm + (size_t)(bn + (tid >> 3)) * K + scol;

  f32x4_t acc[MR][4];
  #pragma unroll
  for (int i = 0; i < MR; i++)
    #pragma unroll
    for (int j = 0; j < 4; j++) acc[i][j] = (f32x4_t){0.f, 0.f, 0.f, 0.f};

  int nt = K >> 6;
  #pragma unroll
  for (int r = 0; r < RA; r++) GLDS16(pa + (size_t)(r * 64) * K, &As[0][(r * 64 + wave * 8) * 64]);
  #pragma unroll
  for (int r = 0; r < 4; r++)  GLDS16(pb + (size_t)(r * 64) * K, &Bs[0][(r * 64 + wave * 8) * 64]);
  __syncthreads();

  for (int t = 0; t < nt; t++) {
    int cur = t & 1;
    if (t + 1 < nt) {
      int k1 = (t + 1) * 64;
      #pragma unroll
      for (int r = 0; r < RA; r++) GLDS16(pa + (size_t)(r * 64) * K + k1, &As[1 - cur][(r * 64 + wave * 8) * 64]);
      #pragma unroll
      for (int r = 0; r < 4; r++)  GLDS16(pb + (size_t)(r * 64) * K + k1, &Bs[1 - cur][(r * 64 + wave * 8) * 64]);
    }
    bf16x8_t bfr[4][2];
    #pragma unroll
    for (int ni = 0; ni < 4; ni++)
      #pragma unroll
      for (int kh = 0; kh < 2; kh++) {
        int blk = (kh * 4 + quad) ^ (l16 & 7);
        bfr[ni][kh] = *(const bf16x8_t*)&Bs[cur][(wn * 64 + ni * 16 + l16) * 64 + blk * 8];
      }
    #pragma unroll
    for (int g = 0; g < MR / 2; g++) {
      bf16x8_t af[2][2];
      #pragma unroll
      for (int i = 0; i < 2; i++)
        #pragma unroll
        for (int kh = 0; kh < 2; kh++) {
          int blk = (kh * 4 + quad) ^ (l16 & 7);
          af[i][kh] = *(const bf16x8_t*)&As[cur][(wm * (BM / 2) + (g * 2 + i) * 16 + l16) * 64 + blk * 8];
        }
      #pragma unroll
      for (int kh = 0; kh < 2; kh++)
        #pragma unroll
        for (int i = 0; i < 2; i++)
          #pragma unroll
          for (int ni = 0; ni < 4; ni++)
            acc[g * 2 + i][ni] = mfma16(af[i][kh], bfr[ni][kh], acc[g * 2 + i][ni]);
    }
    __syncthreads();
  }
  #pragma unroll
  for (int mi = 0; mi < MR; mi++)
    #pragma unroll
    for (int ni = 0; ni < 4; ni++) {
      int row0 = bm + wm * (BM / 2) + mi * 16 + quad * 4;
      int col  = bn + wn * 64 + ni * 16 + l16;
      if (Cb) {
        #pragma unroll
        for (int r = 0; r < 4; r++)
          Cb[(size_t)(row0 + r) * N + col] = (bf16_t)acc[mi][ni][r];
      } else {
        #pragma unroll
        for (int r = 0; r < 4; r++)
          Cf[(size_t)(row0 + r) * N + col] = acc[mi][ni][r];
      }
    }
}

// ---------------- RoPE+RMSNorm AND V-transpose, fused into one launch ----------------
__global__ __launch_bounds__(256) void rope_tv_kernel(const bf16_t* __restrict__ qkv,
    const float* __restrict__ cosb, const float* __restrict__ sinb,
    bf16_t* __restrict__ qb, bf16_t* __restrict__ kb, bf16_t* __restrict__ vt) {
  __shared__ bf16_t TT[64*136];   // transpose scratch (tok, d) pad 128->136
  int bid = blockIdx.x;
  int tid = threadIdx.x;
  if (bid < 24576) {
    int token = bid & 4095;
    int slot = (bid >> 12) * 4 + (tid >> 6);
    int lane = tid & 63;
    int b = token >> 11, s = token & 2047;
    const bf16_t* row = qkv + (size_t)token * QKVD;
    int base_in = (slot < 16) ? slot * HD : C_ + (slot - 16) * HD;
    float x1 = (float)row[base_in + lane];
    float x2 = (float)row[base_in + 64 + lane];
    float c = cosb[s*64 + lane], sn = sinb[s*64 + lane];
    float y1 = x1*c + x2*sn;
    float y2 = x2*c - x1*sn;
    float ss = y1*y1 + y2*y2;
    ss += __shfl_xor(ss, 1);  ss += __shfl_xor(ss, 2);  ss += __shfl_xor(ss, 4);
    ss += __shfl_xor(ss, 8);  ss += __shfl_xor(ss, 16); ss += __shfl_xor(ss, 32);
    float r = rsqrtf(ss * (1.0f/128.0f) + 1.1920929e-07f);
    bf16_t* dst;
    if (slot < 16) {
      r *= 0.08838834764831845f * 1.4426950408889634f;  // 1/sqrt(128) * log2(e)
      dst = qb + ((size_t)(b*NH + slot) * T_ + s) * HD;
    } else {
      dst = kb + ((size_t)(b*NKV + (slot-16)) * T_ + s) * HD;
    }
    dst[lane]      = (bf16_t)(y1 * r);
    dst[lane + 64] = (bf16_t)(y2 * r);
  } else {
    int id = bid - 24576;
    int bk = id & 15;               // b*8 + kv
    int s0 = (id >> 4) * 64;
    int b = bk >> 3, kv = bk & 7;
    int row = tid >> 2, c0 = (tid & 3) * 32;
    const bf16_t* src = qkv + (size_t)(b*T_ + s0 + row) * QKVD + C_ + KVD + kv*HD + c0;
    #pragma unroll
    for (int s4 = 0; s4 < 4; s4++)
      *(bf16x8_t*)&TT[row*136 + c0 + s4*8] = *(const bf16x8_t*)(src + s4*8);
    __syncthreads();
    #pragma unroll
    for (int s2 = 0; s2 < 2; s2++) {
      int d = (tid >> 2) + s2*64;
      #pragma unroll
      for (int s = 0; s < 2; s++) {
        int g = (tid & 3) * 8 + s*32;
        bf16x8_t pk;
        #pragma unroll
        for (int e = 0; e < 8; e++) pk[e] = TT[(g + e)*136 + d];
        *(bf16x8_t*)(vt + ((size_t)bk * HD + d) * T_ + s0 + g) = pk;
      }
    }
  }
}

// ---------------- flash attention: split-K within block (round-6, verified 74us; FROZEN) ----------------
// 512 threads = 8 waves, one (bh, qt) per block; group g = wave>>2 handles key half g,
// q-slice sq = wave&3. Both groups run qt+1 lockstep iterations on private dbuf LDS
// (137KB -> 1 block/CU); lane-aligned LDS merge at the end. Heavy-first dispatch.
// Tree reductions + T13 defer-max. Falsified alternatives: cross-block merge (r7, -5.6x:
// device-scope fence = L2 writeback on non-coherent XCDs), phase-skewed groups (r10, -18%:
// sv-carry + divergent bodies defeat compiler pipelining), 2-block residency (r1/r2).
__global__ __launch_bounds__(512, 1) void attn_kernel(const bf16_t* __restrict__ qb,
    const bf16_t* __restrict__ kb, const bf16_t* __restrict__ vt, bf16_t* __restrict__ yb) {
  __shared__ __align__(16) bf16_t Ks[2][2][64*KSTR];   // [group][buf] (key, d) 67584 B
  __shared__ __align__(16) bf16_t Vs[2][2][128*VSTR];  // [group][buf] (d, key) 69632 B
  int L = blockIdx.x;
  int bh = L & 31;
  int qt = 15 - (L >> 5);              // heavy first
  int b = bh >> 4, h = bh & 15, kvh = h >> 1;
  int tid = threadIdx.x;
  int wv = tid >> 6;                   // 0..7
  int g  = wv >> 2;                    // key group
  int sq = wv & 3;                     // q-slice
  int lane = tid & 63;
  int l32 = lane & 31, half = lane >> 5;
  int t256 = tid & 255;                // within-group thread id (256 per group)
  const bf16_t* Qp = qb + (size_t)bh * T_ * HD;
  const bf16_t* Kp = kb + (size_t)(b*NKV + kvh) * T_ * HD;
  const bf16_t* Vt = vt + (size_t)(b*NKV + kvh) * HD * T_;

  int krow = t256 >> 2, kcb = (t256 & 3) * 32;   // K staging: 64 rows x 128
  int vd = t256 >> 1,  vcb = (t256 & 1) * 32;    // V staging: 128 rows x 64

  int h0 = qt + 1;                     // tiles per group
  int kt0 = g * h0;                    // first tile of this group

  int qrow = qt*128 + sq*32 + l32;
  bf16x8_t qf[8];                      // B-frag: B[k=half*8+jj][n=l32]
  #pragma unroll
  for (int kc = 0; kc < 8; kc++)
    qf[kc] = *(const bf16x8_t*)(Qp + (size_t)qrow * HD + kc*16 + half*8);

  float mrow = -1e30f, lrow = 0.f;
  f32x16_t o[4];                       // O^T: rows = d, col = q = l32
  #pragma unroll
  for (int mb = 0; mb < 4; mb++) o[mb] = zero16();

  bf16x8_t kreg[4], vreg[4];
  {
    const bf16_t* srck = Kp + (size_t)(kt0*64 + krow) * HD + kcb;
    const bf16_t* srcv = Vt + (size_t)vd * T_ + kt0*64 + vcb;
    #pragma unroll
    for (int s2 = 0; s2 < 4; s2++) { kreg[s2] = *(const bf16x8_t*)(srck + s2*8);
                                     vreg[s2] = *(const bf16x8_t*)(srcv + s2*8); }
  }
  #pragma unroll
  for (int s2 = 0; s2 < 4; s2++) { *(bf16x8_t*)&Ks[g][0][krow*KSTR + kcb + s2*8] = kreg[s2];
                                   *(bf16x8_t*)&Vs[g][0][vd*VSTR  + vcb + s2*8] = vreg[s2]; }

  for (int t = 0; t < h0; t++) {
    __syncthreads();  // buf[t&1] fully staged; prior-tile reads done (uniform count both groups)
    int cur = t & 1;
    if (t + 1 < h0) {
      int k1 = (kt0 + t + 1) * 64;
      const bf16_t* srck = Kp + (size_t)(k1 + krow) * HD + kcb;
      const bf16_t* srcv = Vt + (size_t)vd * T_ + k1 + vcb;
      #pragma unroll
      for (int s2 = 0; s2 < 4; s2++) { kreg[s2] = *(const bf16x8_t*)(srck + s2*8);
                                       vreg[s2] = *(const bf16x8_t*)(srcv + s2*8); }
    }
    int k0 = (kt0 + t) * 64;
    // S^T = K Q^T
    f32x16_t sacc[2];
    sacc[0] = zero16(); sacc[1] = zero16();
    #pragma unroll
    for (int kc = 0; kc < 8; kc++)
      #pragma unroll
      for (int mb = 0; mb < 2; mb++) {
        bf16x8_t kf = *(const bf16x8_t*)&Ks[g][cur][(mb*32 + l32)*KSTR + kc*16 + half*8];
        sacc[mb] = mfma32(kf, qf[kc], sacc[mb]);
      }
    // causal mask near diagonal (false for group 0 whenever qt>=1)
    if (k0 + 63 > qt*128 + sq*32) {
      #pragma unroll
      for (int mb = 0; mb < 2; mb++)
        #pragma unroll
        for (int r = 0; r < 16; r++) {
          int key = k0 + mb*32 + (r&3) + 8*(r>>2) + 4*half;
          if (key > qrow) sacc[mb][r] = -1e30f;
        }
    }
    // tile max: tree
    float tm[16];
    #pragma unroll
    for (int r = 0; r < 16; r++) tm[r] = fmaxf(sacc[0][r], sacc[1][r]);
    #pragma unroll
    for (int st = 8; st >= 1; st >>= 1)
      #pragma unroll
      for (int r = 0; r < st; r++) tm[r] = fmaxf(tm[r], tm[r + st]);
    float mx = fmaxf(tm[0], __shfl_xor(tm[0], 32));
    // T13 defer-max
    if (!__all(mx - mrow <= 8.0f)) {
      float mnew = fmaxf(mrow, mx);
      float alpha = exp2f(mrow - mnew);
      mrow = mnew;
      lrow *= alpha;
      #pragma unroll
      for (int mb = 0; mb < 4; mb++) o[mb] = o[mb] * alpha;
    }
    // P = exp2(s - mrow); row-sum via tree
    #pragma unroll
    for (int mb = 0; mb < 2; mb++)
      #pragma unroll
      for (int r = 0; r < 16; r++) sacc[mb][r] = exp2f(sacc[mb][r] - mrow);
    float ts[16];
    #pragma unroll
    for (int r = 0; r < 16; r++) ts[r] = sacc[0][r] + sacc[1][r];
    #pragma unroll
    for (int st = 8; st >= 1; st >>= 1)
      #pragma unroll
      for (int r = 0; r < st; r++) ts[r] += ts[r + st];
    lrow += ts[0] + __shfl_xor(ts[0], 32);
    // P pack
    int P2[2][4][2];
    #pragma unroll
    for (int mb = 0; mb < 2; mb++)
      #pragma unroll
      for (int gg = 0; gg < 4; gg++) {
        P2[mb][gg][0] = pk2(sacc[mb][4*gg+0], sacc[mb][4*gg+1]);
        P2[mb][gg][1] = pk2(sacc[mb][4*gg+2], sacc[mb][4*gg+3]);
      }
    // O^T += V^T P
    #pragma unroll
    for (int kc = 0; kc < 4; kc++) {
      int mb = kc >> 1, c = kc & 1;
      int o0 = half ? P2[mb][2*c+1][0] : P2[mb][2*c][0];
      int o1 = half ? P2[mb][2*c+1][1] : P2[mb][2*c][1];
      int s0 = half ? P2[mb][2*c][0]   : P2[mb][2*c+1][0];
      int s1 = half ? P2[mb][2*c][1]   : P2[mb][2*c+1][1];
      int r0 = __shfl_xor(s0, 32);
      int r1 = __shfl_xor(s1, 32);
      i32x4_t wvv;
      wvv[0] = half ? r0 : o0;
      wvv[1] = half ? r1 : o1;
      wvv[2] = half ? o0 : r0;
      wvv[3] = half ? o1 : r1;
      bf16x8_t pf = __builtin_bit_cast(bf16x8_t, wvv);
      #pragma unroll
      for (int mbd = 0; mbd < 4; mbd++) {
        bf16x8_t vf = *(const bf16x8_t*)&Vs[g][cur][(mbd*32 + l32)*VSTR + kc*16 + half*8];
        o[mbd] = mfma32(vf, pf, o[mbd]);
      }
    }
    if (t + 1 < h0) {
      #pragma unroll
      for (int s2 = 0; s2 < 4; s2++) { *(bf16x8_t*)&Ks[g][1-cur][krow*KSTR + kcb + s2*8] = kreg[s2];
                                       *(bf16x8_t*)&Vs[g][1-cur][vd*VSTR  + vcb + s2*8] = vreg[s2]; }
    }
  }
  // -------- merge the two key-halves (lane-aligned), then epilogue by group 0 --------
  __syncthreads();
  float* MG = (float*)Vs;              // overlay: 256 slots x 66 f32 = 67584 B (<= 69632)
  int mbase = (sq*64 + lane) * 66;     // stride 66 dwords: 2-way bank alias only (free)
  if (g == 1) {
    #pragma unroll
    for (int mb = 0; mb < 4; mb++)
      #pragma unroll
      for (int r = 0; r < 16; r++) MG[mbase + mb*16 + r] = o[mb][r];
    MG[mbase + 64] = mrow;
    MG[mbase + 65] = lrow;
  }
  __syncthreads();
  if (g == 0) {
    float m1 = MG[mbase + 64], l1v = MG[mbase + 65];
    float mm = fmaxf(mrow, m1);
    float a0 = exp2f(mrow - mm), a1 = exp2f(m1 - mm);
    float invl = 1.0f / (lrow * a0 + l1v * a1);
    a0 *= invl; a1 *= invl;
    // O^T -> LDS transpose (wave-private 32xKSTR region) -> coalesced stores
    bf16_t* OL = &((bf16_t*)Ks)[sq * (32 * KSTR)];
    #pragma unroll
    for (int mb = 0; mb < 4; mb++)
      #pragma unroll
      for (int rr = 0; rr < 4; rr++) {
        bf16x4_t pk;
        #pragma unroll
        for (int jj = 0; jj < 4; jj++)
          pk[jj] = (bf16_t)(o[mb][rr*4+jj] * a0 + MG[mbase + mb*16 + rr*4 + jj] * a1);
        *(bf16x4_t*)&OL[l32*KSTR + mb*32 + rr*8 + half*4] = pk;
      }
    int tok = qt*128 + sq*32 + l32;
    bf16_t* dst = yb + ((size_t)(b*T_ + tok) * NH + h) * HD + half*64;
    #pragma unroll
    for (int jj = 0; jj < 8; jj++)
      *(bf16x8_t*)(dst + jj*8) = *(const bf16x8_t*)&OL[l32*KSTR + half*64 + jj*8];
  }
}

extern "C" void kernel_launch(void* const* d_in, const int* in_sizes, int n_in,
                              void* d_out, int out_size, void* d_ws, size_t ws_size,
                              hipStream_t stream) {
  const float* x      = (const float*)d_in[0];
  const float* w_attn = (const float*)d_in[1];
  const float* w_proj = (const float*)d_in[2];
  const float* cosb   = (const float*)d_in[3];
  const float* sinb   = (const float*)d_in[4];
  float* out = (float*)d_out;

  bf16_t* xb   = (bf16_t*)d_ws;           // 8388608
  bf16_t* wab  = xb + 8388608;            // 8388608
  bf16_t* wpb  = wab + 8388608;           // 4194304
  bf16_t* qkvb = wpb + 4194304;           // 16777216
  bf16_t* qb   = qkvb + 16777216;         // 8388608
  bf16_t* kb   = qb + 8388608;            // 4194304
  bf16_t* vt   = kb + 4194304;            // 4194304 (b, kvh, d, t)
  bf16_t* yb   = vt + 4194304;            // 8388608

  // fused fp32->bf16: 8 floats/thread, 10240 blocks (x:4096, w_attn:4096, w_proj:2048)
  cvt3_kernel<<<10240, 256, 0, stream>>>(x, xb, w_attn, wab, w_proj, wpb);

  // qkv = x @ w_attn^T : M=4096, N=4096, K=2048 (bf16 out). 8-phase 256x256, grid 16x16
  gemm8p<<<dim3(16, 16), 512, 0, stream>>>(xb, wab, qkvb, NTOK, QKVD, C_);

  // fused RoPE+RMSNorm (24576 blocks) + V transpose (512 blocks)
  rope_tv_kernel<<<25088, 256, 0, stream>>>(qkvb, cosb, sinb, qb, kb, vt);

  // 512 blocks x 512 threads: split-K within block, heavy-first dispatch, 1 block/CU (137KB LDS)
  attn_kernel<<<512, 512, 0, stream>>>(qb, kb, vt, yb);

  // out = y @ w_proj^T : M=4096, N=2048, K=2048 (fp32 out). 128x256 tiles, grid 8x32=256 blocks
  gemm_nt2<128><<<dim3(8, 32), 512, 0, stream>>>(yb, wpb, out, nullptr, NTOK, C_, C_);
}